// Round 6
// baseline (166.205 us; speedup 1.0000x reference)
//
#include <hip/hip_runtime.h>

// Problem constants (RefinementLayer1): B=2, L=192, D=768, NC=4, H=256
#define LSEQ 192
#define DIM  768
#define NCASE 4
#define HID  256
#define BATCH 2

// tanh(x) = 1 - 2/(exp2(K*x)+1), K = 2*log2(e). K is pre-folded into lin and
// Bpack so the hot kernels compute tanh with only {exp2, add, rcp, fma}.
#define TANH_K 2.885390081777927f

typedef float  floatx4 __attribute__((ext_vector_type(4)));
typedef __bf16 bf16x8  __attribute__((ext_vector_type(8)));

// input already scaled by TANH_K
__device__ __forceinline__ float tanh_pre(float x) {
    float e = __builtin_amdgcn_exp2f(x);
    return 1.0f - 2.0f * __builtin_amdgcn_rcpf(e + 1.0f);
}

// cross-lane add via DPP (full-rate VALU, no LDS pipe). ctrl must be an ICE.
template <int CTRL>
__device__ __forceinline__ float dpp_add(float v) {
    int x = __builtin_amdgcn_update_dpp(0, __builtin_bit_cast(int, v),
                                        CTRL, 0xF, 0xF, true);
    return v + __builtin_bit_cast(float, x);
}
// reduce over the 16 lanes of a DPP row (our value-groups are exactly rows:
// lanes quad*16 .. quad*16+15). After 4 stages every lane holds the total.
__device__ __forceinline__ float row16_reduce(float v) {
    v = dpp_add<0xB1>(v);    // quad_perm(1,0,3,2)  — xor 1
    v = dpp_add<0x4E>(v);    // quad_perm(2,3,0,1)  — xor 2
    v = dpp_add<0x141>(v);   // row_half_mirror     — pairs quads within 8
    v = dpp_add<0x140>(v);   // row_mirror          — pairs halves within 16
    return v;
}

// ---------------------------------------------------------------------------
// MFMA fragment layouts (m89/m91-verified, 16x16x32 bf16):
//   A: lane holds A[m = lane&15][k = (lane>>4)*8 + j]   (bf16x8)
//   B: lane holds B[k = (lane>>4)*8 + j][h = lane&15]   (bf16x8)
//   C/D: lane reg holds D[row = (lane>>4)*4 + reg][col = lane&15]
// ---------------------------------------------------------------------------

// ---------------------------------------------------------------------------
// Kernel 0: pack everything (one launch, 3 jobs by linear thread id):
//  job A (t <  36864): seq -> seq_hi/seq_lo bf16 row-major (8 elems/thread)
//  job B (t < 159744): [Wp|Wa] -> W_hi/W_lo bf16 B-frags
//  job C (rest):       Wmid/bmid -> Bpack bf16 B-frags, scaled by TANH_K
//       frag u = ((n*9 + kc)*16 + ct)*64 + lane; k rows 256..259 = bs rows,
//       k == 260 = bmid (paired with A=1), k > 260 = zero pad.
// ---------------------------------------------------------------------------
__global__ __launch_bounds__(256) void pack_all(
    const float* __restrict__ seq, const float* __restrict__ Wp,
    const float* __restrict__ Wa, const float* __restrict__ Wmid,
    const float* __restrict__ bmid,
    bf16x8* __restrict__ seq_hi, bf16x8* __restrict__ seq_lo,
    bf16x8* __restrict__ W_hi,   bf16x8* __restrict__ W_lo,
    bf16x8* __restrict__ Bpack)
{
    int t = blockIdx.x * 256 + threadIdx.x;
    if (t < 36864) {                       // ---- seq hi/lo, coalesced
        const float* s = seq + (size_t)t * 8;
        bf16x8 hi, lo;
        #pragma unroll
        for (int j = 0; j < 8; j++) {
            float v = s[j];
            __bf16 h = (__bf16)v;
            hi[j] = h;
            lo[j] = (__bf16)(v - (float)h);
        }
        seq_hi[t] = hi; seq_lo[t] = lo;
    } else if (t < 159744) {               // ---- [Wp|Wa] frags hi/lo
        int u = t - 36864;                 // (kc*80 + ctg)*64 + lane
        int lane = u & 63, f = u >> 6;
        int ctg = f % 80, kc = f / 80;
        int col16 = lane & 15, quad = lane >> 4;
        int col = ctg * 16 + col16;
        bf16x8 hi, lo;
        #pragma unroll
        for (int j = 0; j < 8; j++) {
            int k = kc * 32 + quad * 8 + j;
            float v = (col < 256) ? Wp[(size_t)k * HID + col]
                                  : Wa[(size_t)k * (NCASE * HID) + col - 256];
            __bf16 h = (__bf16)v;
            hi[j] = h;
            lo[j] = (__bf16)(v - (float)h);
        }
        W_hi[u] = hi; W_lo[u] = lo;
    } else {                               // ---- Wmid/bmid frags (TANH_K folded)
        int u = t - 159744;                // ((n*9+kc)*16+ct)*64 + lane
        int lane = u & 63, f = u >> 6;
        int ct = f & 15, nk = f >> 4;
        int kc = nk % 9, n = nk / 9;
        int col16 = lane & 15, quad = lane >> 4;
        int h = ct * 16 + col16;
        bf16x8 v;
        #pragma unroll
        for (int j = 0; j < 8; j++) {
            int k = kc * 32 + quad * 8 + j;
            float x;
            if (k < 260)       x = Wmid[(size_t)(n * 260 + k) * 256 + h];
            else if (k == 260) x = bmid[n * 256 + h];
            else               x = 0.0f;
            v[j] = (__bf16)(TANH_K * x);
        }
        Bpack[u] = v;
    }
}

// ---------------------------------------------------------------------------
// Kernel 1: lin[row, col] = TANH_K * (seq[row,:] @ [Wp|Wa][:, col] + bias)
// 1-wave blocks, grid (24 row-tiles x 80 col-groups of 16) = 1920 waves
// (~7.5 blocks/CU). MFMA bf16 hi/lo split (hh + lh + hl), reg prefetch.
// ---------------------------------------------------------------------------
__global__ __launch_bounds__(64) void lin_mfma(
    const bf16x8* __restrict__ seq_hi, const bf16x8* __restrict__ seq_lo,
    const bf16x8* __restrict__ W_hi,   const bf16x8* __restrict__ W_lo,
    const float* __restrict__ bp, const float* __restrict__ ba,
    float* __restrict__ lin)
{
    const int rt = blockIdx.x;            // 24
    const int cg = blockIdx.y;            // 80
    const int lane  = threadIdx.x;
    const int quad  = lane >> 4;
    const int col16 = lane & 15;

    const int abase = (rt * 16 + col16) * 96 + quad;   // + kc*4 per chunk
    const int bbase = cg * 64 + lane;                  // + kc*5120 per chunk
    floatx4 acc = {};

    bf16x8 ah = seq_hi[abase], al = seq_lo[abase];
    bf16x8 bh = W_hi[bbase],   bl = W_lo[bbase];
    #pragma unroll
    for (int kc = 0; kc < 24; kc++) {
        bf16x8 ah2, al2, bh2, bl2;
        if (kc < 23) {
            ah2 = seq_hi[abase + (kc + 1) * 4];
            al2 = seq_lo[abase + (kc + 1) * 4];
            bh2 = W_hi[bbase + (kc + 1) * 5120];
            bl2 = W_lo[bbase + (kc + 1) * 5120];
        }
        acc = __builtin_amdgcn_mfma_f32_16x16x32_bf16(ah, bh, acc, 0, 0, 0);
        acc = __builtin_amdgcn_mfma_f32_16x16x32_bf16(al, bh, acc, 0, 0, 0);
        acc = __builtin_amdgcn_mfma_f32_16x16x32_bf16(ah, bl, acc, 0, 0, 0);
        ah = ah2; al = al2; bh = bh2; bl = bl2;
    }
    const int col = cg * 16 + col16;
    const float bias = (col < 256) ? bp[col] : ba[col - 256];
    #pragma unroll
    for (int reg = 0; reg < 4; reg++)
        lin[(size_t)(rt * 16 + quad * 4 + reg) * 1280 + col] =
            TANH_K * (acc[reg] + bias);
}

// ---------------------------------------------------------------------------
// Kernel 2: fused main. Block = 4 waves, 64 rows (8p x 8a) x 256 cols, fixed
// (b,n). A is SHARED via LDS (each thread tanh-generates one frag slot per
// chunk: row = w*16+col16, k-slice = quad*8); cols are SPLIT across waves
// (wave w owns ct-group w*4..w*4+3, B-frags loaded global->regs,
// non-redundant). Software-pipelined: av(kc+1) is computed into the other
// LDS buffer BEFORE MFMAs(kc) issue, so trans and MFMA pipes overlap within
// a wave; ONE barrier per chunk gating only chunk-old data.
// K: 8 tanh chunks + 1 folded bs/bmid chunk. Epilogue: tanh(acc).Wout,
// 16-lane DPP reduce (no LDS pipe), cross-wave LDS combine, store.
// ---------------------------------------------------------------------------
__global__ __launch_bounds__(256, 2) void refine_main(
    const float* __restrict__ lin,        // [384][1280], pre-scaled by TANH_K
    const float* __restrict__ base_score, // [B][L][NC][L]
    const float* __restrict__ Wout,       // [NC][256]
    const bf16x8* __restrict__ Bpack,     // packed Wmid frags
    float* __restrict__ out)              // [B][L][NC][L]
{
    const int bx = blockIdx.x;            // 576 = 24*24
    const int n  = blockIdx.y;
    const int b  = blockIdx.z;
    const int ptile = bx / 24, atile = bx % 24;
    const int p0 = ptile * 8, a0 = atile * 8;

    const int tid   = threadIdx.x;
    const int w     = tid >> 6;
    const int lane  = tid & 63;
    const int quad  = lane >> 4;
    const int col16 = lane & 15;

    __shared__ __align__(16) __bf16 A0[256 * 8];   // 4 KB frag buf (even kc)
    __shared__ __align__(16) __bf16 A1[256 * 8];   // 4 KB frag buf (odd kc)
    __shared__ float red[4][64];

    // A-gen: this thread owns frag slot (rt = w, lane): row = w*16 + col16,
    // k-slice quad*8..+7 of each 32-chunk.  LDS slot index == tid.
    const int row_gen = w * 16 + col16;
    const int pg = p0 + (row_gen >> 3), ag = a0 + (row_gen & 7);
    const float* hp_ptr = lin + (size_t)(b * LSEQ + pg) * 1280 + quad * 8;
    const float* ha_ptr = lin + (size_t)(b * LSEQ + ag) * 1280 + 256 + n * 256 + quad * 8;

    // B frags for wave w: index ((n*9 + kc)*16 + w*4 + ct)*64 + lane
    const bf16x8* bbase = Bpack + ((size_t)(n * 9) * 16 + w * 4) * 64 + lane;

    // ---- prologue
    float bs4[4], wo[4];
    #pragma unroll
    for (int j = 0; j < 4; j++)
        bs4[j] = base_score[((size_t)(b * LSEQ + pg) * NCASE + j) * LSEQ + ag];
    #pragma unroll
    for (int ct = 0; ct < 4; ct++)
        wo[ct] = Wout[n * 256 + w * 64 + ct * 16 + col16];

    bf16x8 bcur[4];
    #pragma unroll
    for (int ct = 0; ct < 4; ct++) bcur[ct] = bbase[ct * 64];

    floatx4 hp0 = *(const floatx4*)(hp_ptr);
    floatx4 hp1 = *(const floatx4*)(hp_ptr + 4);
    floatx4 ha0 = *(const floatx4*)(ha_ptr);
    floatx4 ha1 = *(const floatx4*)(ha_ptr + 4);
    {   // av(0) -> A0
        floatx4 s0 = hp0 + ha0, s1 = hp1 + ha1;
        bf16x8 av;
        #pragma unroll
        for (int j = 0; j < 4; j++) {
            av[j]     = (__bf16)tanh_pre(s0[j]);
            av[4 + j] = (__bf16)tanh_pre(s1[j]);
        }
        *(bf16x8*)&A0[tid * 8] = av;
    }
    // inputs for chunk 1
    hp0 = *(const floatx4*)(hp_ptr + 32);
    hp1 = *(const floatx4*)(hp_ptr + 36);
    ha0 = *(const floatx4*)(ha_ptr + 32);
    ha1 = *(const floatx4*)(ha_ptr + 36);
    __syncthreads();

    floatx4 acc[4][4] = {};   // [rt][ct]

    #pragma unroll
    for (int kc = 0; kc < 9; kc++) {
        // B prefetch for chunk kc+1 (consumed next iteration)
        bf16x8 bnext[4];
        if (kc < 8) {
            #pragma unroll
            for (int ct = 0; ct < 4; ct++)
                bnext[ct] = bbase[((kc + 1) * 16 + ct) * 64];
        }
        // generate av(kc+1) into the other buffer (trans overlaps MFMA below)
        if (kc < 7) {
            floatx4 s0 = hp0 + ha0, s1 = hp1 + ha1;
            if (kc < 6) {                 // prefetch inputs for chunk kc+2
                hp0 = *(const floatx4*)(hp_ptr + (kc + 2) * 32);
                hp1 = *(const floatx4*)(hp_ptr + (kc + 2) * 32 + 4);
                ha0 = *(const floatx4*)(ha_ptr + (kc + 2) * 32);
                ha1 = *(const floatx4*)(ha_ptr + (kc + 2) * 32 + 4);
            }
            bf16x8 av;
            #pragma unroll
            for (int j = 0; j < 4; j++) {
                av[j]     = (__bf16)tanh_pre(s0[j]);
                av[4 + j] = (__bf16)tanh_pre(s1[j]);
            }
            __bf16* buf = ((kc + 1) & 1) ? A1 : A0;
            *(bf16x8*)&buf[tid * 8] = av;
        } else if (kc == 7) {             // folded chunk 8: A=[bs(4),1,0...]
            bf16x8 av = {};
            if (quad == 0) {
                #pragma unroll
                for (int j = 0; j < 4; j++) av[j] = (__bf16)bs4[j];
                av[4] = (__bf16)1.0f;
            }
            *(bf16x8*)&A0[tid * 8] = av;  // (7+1)&1 == 0
        }

        // MFMA(kc) from buf[kc&1]
        const __bf16* rb = (kc & 1) ? A1 : A0;
        bf16x8 af[4];
        #pragma unroll
        for (int rt = 0; rt < 4; rt++)
            af[rt] = *(const bf16x8*)&rb[(rt * 64 + lane) * 8];
        #pragma unroll
        for (int rt = 0; rt < 4; rt++)
            #pragma unroll
            for (int ct = 0; ct < 4; ct++)
                acc[rt][ct] = __builtin_amdgcn_mfma_f32_16x16x32_bf16(
                    af[rt], bcur[ct], acc[rt][ct], 0, 0, 0);
        #pragma unroll
        for (int ct = 0; ct < 4; ct++) bcur[ct] = bnext[ct];
        if (kc < 8) __syncthreads();
    }

    // ---- epilogue: tanh(acc) . Wout, DPP 16-lane reduce, cross-wave combine
    #pragma unroll
    for (int rt = 0; rt < 4; rt++) {
        #pragma unroll
        for (int reg = 0; reg < 4; reg++) {
            float rs = 0.0f;
            #pragma unroll
            for (int ct = 0; ct < 4; ct++)
                rs += tanh_pre(acc[rt][ct][reg]) * wo[ct];
            rs = row16_reduce(rs);        // all 16 lanes hold the col-sum
            if (col16 == 0) red[w][rt * 16 + quad * 4 + reg] = rs;
        }
    }
    __syncthreads();

    if (tid < 64) {
        float total = red[0][tid] + red[1][tid] + red[2][tid] + red[3][tid];
        const int p = p0 + (tid >> 3), a = a0 + (tid & 7);
        out[((size_t)(b * LSEQ + p) * NCASE + n) * LSEQ + a] = total;
    }
}

// ---------------------------------------------------------------------------
extern "C" void kernel_launch(void* const* d_in, const int* in_sizes, int n_in,
                              void* d_out, int out_size, void* d_ws, size_t ws_size,
                              hipStream_t stream) {
    const float* seq  = (const float*)d_in[0];
    const float* bsc  = (const float*)d_in[1];
    const float* Wp   = (const float*)d_in[2];
    const float* bp   = (const float*)d_in[3];
    const float* Wa   = (const float*)d_in[4];
    const float* ba   = (const float*)d_in[5];
    const float* Wmid = (const float*)d_in[6];
    const float* bmid = (const float*)d_in[7];
    const float* Wout = (const float*)d_in[8];
    float* out = (float*)d_out;

    // workspace layout (16B-aligned):
    char* ws = (char*)d_ws;
    bf16x8* seq_hi = (bf16x8*)(ws);                    //   589,824 B
    bf16x8* seq_lo = (bf16x8*)(ws +  589824);          //   589,824 B
    bf16x8* W_hi   = (bf16x8*)(ws + 1179648);          // 1,966,080 B
    bf16x8* W_lo   = (bf16x8*)(ws + 3145728);          // 1,966,080 B
    bf16x8* Bpack  = (bf16x8*)(ws + 5111808);          //   589,824 B
    float*  lin    = (float*) (ws + 5701632);          // 1,966,080 B  (fp32)

    pack_all<<<768, 256, 0, stream>>>(seq, Wp, Wa, Wmid, bmid,
                                      seq_hi, seq_lo, W_hi, W_lo, Bpack);
    lin_mfma<<<dim3(24, 80), 64, 0, stream>>>(seq_hi, seq_lo, W_hi, W_lo,
                                              bp, ba, lin);
    refine_main<<<dim3(576, NCASE, BATCH), 256, 0, stream>>>(
        lin, bsc, Wout, Bpack, out);
}

// Round 7
// 151.801 us; speedup vs baseline: 1.0949x; 1.0949x over previous
//
#include <hip/hip_runtime.h>

// Problem constants (RefinementLayer1): B=2, L=192, D=768, NC=4, H=256
#define LSEQ 192
#define DIM  768
#define NCASE 4
#define HID  256
#define BATCH 2

// tanh(x) = 1 - 2/(exp2(K*x)+1), K = 2*log2(e). K is pre-folded into lin and
// Bpack so the hot kernels compute tanh with only {exp2, add, rcp, fma}.
#define TANH_K 2.885390081777927f

typedef float  floatx4 __attribute__((ext_vector_type(4)));
typedef __bf16 bf16x8  __attribute__((ext_vector_type(8)));

// input already scaled by TANH_K
__device__ __forceinline__ float tanh_pre(float x) {
    float e = __builtin_amdgcn_exp2f(x);
    return 1.0f - 2.0f * __builtin_amdgcn_rcpf(e + 1.0f);
}

// Workgroup barrier that drains ONLY LDS (lgkmcnt(0)), not vmcnt.
// __syncthreads() emits s_waitcnt vmcnt(0) lgkmcnt(0) + s_barrier, which
// drains our deliberately-in-flight global prefetches every chunk (the 83 µs
// invariant of R4/R6). Our K-loop barrier only orders LDS A-frag traffic.
// 0xC07F = vmcnt(63) expcnt(7) lgkmcnt(0) on gfx9-family encoding.
__device__ __forceinline__ void barrier_lds_only() {
    __builtin_amdgcn_sched_barrier(0);          // pin: no motion across
    __builtin_amdgcn_s_waitcnt(0xC07F);         // lgkmcnt(0) only
    __builtin_amdgcn_s_barrier();
    __builtin_amdgcn_sched_barrier(0);
}

// cross-lane add via DPP (full-rate VALU, no LDS pipe). ctrl must be an ICE.
template <int CTRL>
__device__ __forceinline__ float dpp_add(float v) {
    int x = __builtin_amdgcn_update_dpp(0, __builtin_bit_cast(int, v),
                                        CTRL, 0xF, 0xF, true);
    return v + __builtin_bit_cast(float, x);
}
// reduce over the 16 lanes of a DPP row; after 4 stages all lanes hold total.
__device__ __forceinline__ float row16_reduce(float v) {
    v = dpp_add<0xB1>(v);    // quad_perm(1,0,3,2)  — xor 1
    v = dpp_add<0x4E>(v);    // quad_perm(2,3,0,1)  — xor 2
    v = dpp_add<0x141>(v);   // row_half_mirror
    v = dpp_add<0x140>(v);   // row_mirror
    return v;
}

// ---------------------------------------------------------------------------
// MFMA fragment layouts (m89/m91-verified, 16x16x32 bf16):
//   A: lane holds A[m = lane&15][k = (lane>>4)*8 + j]   (bf16x8)
//   B: lane holds B[k = (lane>>4)*8 + j][h = lane&15]   (bf16x8)
//   C/D: lane reg holds D[row = (lane>>4)*4 + reg][col = lane&15]
// ---------------------------------------------------------------------------

// ---------------------------------------------------------------------------
// Kernel 1 "prep": two jobs by blockIdx (no intra-kernel dependency):
//  blocks [0,480):  lin GEMM. 4 independent waves/block; wave = one (rt,cg)
//    unit: 16 rows x 16 cols of lin = TANH_K*(seq @ [Wp|Wa] + bias).
//    seq/W are converted to bf16 hi/lo IN-REGISTER (self-sufficient; no pack
//    dependency), MFMA hh+lh+hl for near-fp32 accuracy. Barrier-free.
//  blocks [480,624): pack Wmid/bmid -> Bpack bf16 B-frags scaled by TANH_K
//    (consumed only by the NEXT kernel, so ordering vs lin-job is irrelevant).
// ---------------------------------------------------------------------------
__global__ __launch_bounds__(256) void prep(
    const float* __restrict__ seq, const float* __restrict__ Wp,
    const float* __restrict__ Wa,  const float* __restrict__ bp,
    const float* __restrict__ ba,  const float* __restrict__ Wmid,
    const float* __restrict__ bmid,
    float* __restrict__ lin, bf16x8* __restrict__ Bpack)
{
    const int blk = blockIdx.x;
    const int tid = threadIdx.x;

    if (blk >= 480) {                      // ---- pack job
        int u = (blk - 480) * 256 + tid;   // 0..36863 (one bf16x8 each)
        int lane = u & 63, f = u >> 6;
        int ct = f & 15, nk = f >> 4;      // nk = n*9 + kc
        int kc = nk % 9, n = nk / 9;
        int h = ct * 16 + (lane & 15);
        int kbase = kc * 32 + ((lane >> 4) & 3) * 8;
        bf16x8 v;
        #pragma unroll
        for (int j = 0; j < 8; j++) {
            int k = kbase + j;
            float x;
            if (k < 260)       x = Wmid[(size_t)(n * 260 + k) * 256 + h];
            else if (k == 260) x = bmid[n * 256 + h];
            else               x = 0.0f;
            v[j] = (__bf16)(TANH_K * x);
        }
        Bpack[u] = v;
        return;
    }

    // ---- lin GEMM job: unit u = blk*4 + wave, rt = u/80, cg = u%80
    const int w = tid >> 6, lane = tid & 63;
    const int u = blk * 4 + w;
    const int rt = u / 80, cg = u % 80;
    const int quad  = lane >> 4;
    const int col16 = lane & 15;

    const int arow = rt * 16 + col16;          // A: m = lane&15
    const int col  = cg * 16 + col16;          // output col 0..1279
    const float* aptr = seq + (size_t)arow * DIM + quad * 8;
    const float* wbase = (cg < 16) ? (Wp + col) : (Wa + (col - 256));
    const int    wstr  = (cg < 16) ? HID : (NCASE * HID);

    floatx4 acc = {};
    floatx4 a0 = *(const floatx4*)(aptr);
    floatx4 a1 = *(const floatx4*)(aptr + 4);
    float bv[8];
    #pragma unroll
    for (int j = 0; j < 8; j++) bv[j] = wbase[(size_t)(quad * 8 + j) * wstr];

    #pragma unroll
    for (int kc = 0; kc < 24; kc++) {
        // convert current chunk to hi/lo frags
        bf16x8 ah, al, bh, bl;
        #pragma unroll
        for (int j = 0; j < 4; j++) {
            __bf16 h0 = (__bf16)a0[j];
            ah[j] = h0; al[j] = (__bf16)(a0[j] - (float)h0);
            __bf16 h1 = (__bf16)a1[j];
            ah[4 + j] = h1; al[4 + j] = (__bf16)(a1[j] - (float)h1);
        }
        #pragma unroll
        for (int j = 0; j < 8; j++) {
            __bf16 h = (__bf16)bv[j];
            bh[j] = h; bl[j] = (__bf16)(bv[j] - (float)h);
        }
        // prefetch next chunk
        if (kc < 23) {
            a0 = *(const floatx4*)(aptr + (kc + 1) * 32);
            a1 = *(const floatx4*)(aptr + (kc + 1) * 32 + 4);
            #pragma unroll
            for (int j = 0; j < 8; j++)
                bv[j] = wbase[(size_t)((kc + 1) * 32 + quad * 8 + j) * wstr];
        }
        acc = __builtin_amdgcn_mfma_f32_16x16x32_bf16(ah, bh, acc, 0, 0, 0);
        acc = __builtin_amdgcn_mfma_f32_16x16x32_bf16(al, bh, acc, 0, 0, 0);
        acc = __builtin_amdgcn_mfma_f32_16x16x32_bf16(ah, bl, acc, 0, 0, 0);
    }
    const float bias = (cg < 16) ? bp[col] : ba[col - 256];
    #pragma unroll
    for (int reg = 0; reg < 4; reg++)
        lin[(size_t)(rt * 16 + quad * 4 + reg) * 1280 + col] =
            TANH_K * (acc[reg] + bias);
}

// ---------------------------------------------------------------------------
// Kernel 2: fused main (structure = R6, barriers fixed). Block = 4 waves,
// 64 rows (8p x 8a) x 256 cols, fixed (b,n). A SHARED via LDS (each thread
// tanh-generates one frag slot/chunk); cols SPLIT across waves (wave w owns
// ct w*4..w*4+3, B-frags global->regs, non-redundant per block). Pipelined:
// B(kc+1) and lin(kc+2) loads stay IN FLIGHT across the lgkm-only barrier.
// K: 8 tanh chunks + 1 folded bs/bmid chunk. Epilogue: tanh(acc).Wout,
// DPP 16-lane reduce, cross-wave LDS combine, store.
// ---------------------------------------------------------------------------
__global__ __launch_bounds__(256, 2) void refine_main(
    const float* __restrict__ lin,        // [384][1280], pre-scaled by TANH_K
    const float* __restrict__ base_score, // [B][L][NC][L]
    const float* __restrict__ Wout,       // [NC][256]
    const bf16x8* __restrict__ Bpack,     // packed Wmid frags
    float* __restrict__ out)              // [B][L][NC][L]
{
    const int bx = blockIdx.x;            // 576 = 24*24
    const int n  = blockIdx.y;
    const int b  = blockIdx.z;
    const int ptile = bx / 24, atile = bx % 24;
    const int p0 = ptile * 8, a0 = atile * 8;

    const int tid   = threadIdx.x;
    const int w     = tid >> 6;
    const int lane  = tid & 63;
    const int quad  = lane >> 4;
    const int col16 = lane & 15;

    __shared__ __align__(16) __bf16 A0[256 * 8];   // 4 KB frag buf (even kc)
    __shared__ __align__(16) __bf16 A1[256 * 8];   // 4 KB frag buf (odd kc)
    __shared__ float red[4][64];

    // A-gen: thread owns frag slot (rt = w, lane): row = w*16 + col16,
    // k-slice quad*8..+7 of each 32-chunk. LDS slot index == tid.
    const int row_gen = w * 16 + col16;
    const int pg = p0 + (row_gen >> 3), ag = a0 + (row_gen & 7);
    const float* hp_ptr = lin + (size_t)(b * LSEQ + pg) * 1280 + quad * 8;
    const float* ha_ptr = lin + (size_t)(b * LSEQ + ag) * 1280 + 256 + n * 256 + quad * 8;

    // B frags for wave w: index ((n*9 + kc)*16 + w*4 + ct)*64 + lane
    const bf16x8* bbase = Bpack + ((size_t)(n * 9) * 16 + w * 4) * 64 + lane;

    // ---- prologue
    float bs4[4], wo[4];
    #pragma unroll
    for (int j = 0; j < 4; j++)
        bs4[j] = base_score[((size_t)(b * LSEQ + pg) * NCASE + j) * LSEQ + ag];
    #pragma unroll
    for (int ct = 0; ct < 4; ct++)
        wo[ct] = Wout[n * 256 + w * 64 + ct * 16 + col16];

    bf16x8 bcur[4];
    #pragma unroll
    for (int ct = 0; ct < 4; ct++) bcur[ct] = bbase[ct * 64];

    floatx4 hp0 = *(const floatx4*)(hp_ptr);
    floatx4 hp1 = *(const floatx4*)(hp_ptr + 4);
    floatx4 ha0 = *(const floatx4*)(ha_ptr);
    floatx4 ha1 = *(const floatx4*)(ha_ptr + 4);
    {   // av(0) -> A0
        floatx4 s0 = hp0 + ha0, s1 = hp1 + ha1;
        bf16x8 av;
        #pragma unroll
        for (int j = 0; j < 4; j++) {
            av[j]     = (__bf16)tanh_pre(s0[j]);
            av[4 + j] = (__bf16)tanh_pre(s1[j]);
        }
        *(bf16x8*)&A0[tid * 8] = av;
    }
    // inputs for chunk 1
    hp0 = *(const floatx4*)(hp_ptr + 32);
    hp1 = *(const floatx4*)(hp_ptr + 36);
    ha0 = *(const floatx4*)(ha_ptr + 32);
    ha1 = *(const floatx4*)(ha_ptr + 36);
    barrier_lds_only();

    floatx4 acc[4][4] = {};   // [rt][ct]

    #pragma unroll
    for (int kc = 0; kc < 9; kc++) {
        // B prefetch for chunk kc+1 (consumed next iteration; stays in
        // flight across the barrier)
        bf16x8 bnext[4];
        if (kc < 8) {
            #pragma unroll
            for (int ct = 0; ct < 4; ct++)
                bnext[ct] = bbase[((kc + 1) * 16 + ct) * 64];
        }
        // generate av(kc+1) into the other buffer (trans overlaps MFMA below)
        if (kc < 7) {
            floatx4 s0 = hp0 + ha0, s1 = hp1 + ha1;
            if (kc < 6) {                 // prefetch inputs for chunk kc+2
                hp0 = *(const floatx4*)(hp_ptr + (kc + 2) * 32);
                hp1 = *(const floatx4*)(hp_ptr + (kc + 2) * 32 + 4);
                ha0 = *(const floatx4*)(ha_ptr + (kc + 2) * 32);
                ha1 = *(const floatx4*)(ha_ptr + (kc + 2) * 32 + 4);
            }
            bf16x8 av;
            #pragma unroll
            for (int j = 0; j < 4; j++) {
                av[j]     = (__bf16)tanh_pre(s0[j]);
                av[4 + j] = (__bf16)tanh_pre(s1[j]);
            }
            __bf16* buf = ((kc + 1) & 1) ? A1 : A0;
            *(bf16x8*)&buf[tid * 8] = av;
        } else if (kc == 7) {             // folded chunk 8: A=[bs(4),1,0...]
            bf16x8 av = {};
            if (quad == 0) {
                #pragma unroll
                for (int j = 0; j < 4; j++) av[j] = (__bf16)bs4[j];
                av[4] = (__bf16)1.0f;
            }
            *(bf16x8*)&A0[tid * 8] = av;  // (7+1)&1 == 0
        }

        // MFMA(kc) from buf[kc&1]
        const __bf16* rb = (kc & 1) ? A1 : A0;
        bf16x8 af[4];
        #pragma unroll
        for (int rt = 0; rt < 4; rt++)
            af[rt] = *(const bf16x8*)&rb[(rt * 64 + lane) * 8];
        #pragma unroll
        for (int rt = 0; rt < 4; rt++)
            #pragma unroll
            for (int ct = 0; ct < 4; ct++)
                acc[rt][ct] = __builtin_amdgcn_mfma_f32_16x16x32_bf16(
                    af[rt], bcur[ct], acc[rt][ct], 0, 0, 0);
        #pragma unroll
        for (int ct = 0; ct < 4; ct++) bcur[ct] = bnext[ct];
        if (kc < 8) barrier_lds_only();   // lgkm-only: globals stay in flight
    }

    // ---- epilogue: tanh(acc) . Wout, DPP 16-lane reduce, cross-wave combine
    #pragma unroll
    for (int rt = 0; rt < 4; rt++) {
        #pragma unroll
        for (int reg = 0; reg < 4; reg++) {
            float rs = 0.0f;
            #pragma unroll
            for (int ct = 0; ct < 4; ct++)
                rs += tanh_pre(acc[rt][ct][reg]) * wo[ct];
            rs = row16_reduce(rs);        // all 16 lanes hold the col-sum
            if (col16 == 0) red[w][rt * 16 + quad * 4 + reg] = rs;
        }
    }
    barrier_lds_only();

    if (tid < 64) {
        float total = red[0][tid] + red[1][tid] + red[2][tid] + red[3][tid];
        const int p = p0 + (tid >> 3), a = a0 + (tid & 7);
        out[((size_t)(b * LSEQ + p) * NCASE + n) * LSEQ + a] = total;
    }
}

// ---------------------------------------------------------------------------
extern "C" void kernel_launch(void* const* d_in, const int* in_sizes, int n_in,
                              void* d_out, int out_size, void* d_ws, size_t ws_size,
                              hipStream_t stream) {
    const float* seq  = (const float*)d_in[0];
    const float* bsc  = (const float*)d_in[1];
    const float* Wp   = (const float*)d_in[2];
    const float* bp   = (const float*)d_in[3];
    const float* Wa   = (const float*)d_in[4];
    const float* ba   = (const float*)d_in[5];
    const float* Wmid = (const float*)d_in[6];
    const float* bmid = (const float*)d_in[7];
    const float* Wout = (const float*)d_in[8];
    float* out = (float*)d_out;

    // workspace layout (16B-aligned):
    char* ws = (char*)d_ws;
    float*  lin   = (float*)(ws);                      // 1,966,080 B
    bf16x8* Bpack = (bf16x8*)(ws + 1966080);           //   589,824 B

    prep<<<624, 256, 0, stream>>>(seq, Wp, Wa, bp, ba, Wmid, bmid, lin, Bpack);
    refine_main<<<dim3(576, NCASE, BATCH), 256, 0, stream>>>(
        lin, bsc, Wout, Bpack, out);
}